// Round 4
// baseline (191.459 us; speedup 1.0000x reference)
//
#include <hip/hip_runtime.h>
#include <hip/hip_bf16.h>
#include <math.h>

typedef __bf16  bf16x8 __attribute__((ext_vector_type(8)));
typedef float   f32x4  __attribute__((ext_vector_type(4)));

// ---------------- helpers ----------------
static __device__ __forceinline__ void load_lds16(const void* g, void* l) {
  __builtin_amdgcn_global_load_lds(
      (const __attribute__((address_space(1))) void*)(g),
      (__attribute__((address_space(3))) void*)(l), 16, 0, 0);
}

#define BAR() __builtin_amdgcn_s_barrier()
#define SB0() __builtin_amdgcn_sched_barrier(0)
#define LGKM(N) do { asm volatile("s_waitcnt lgkmcnt(" #N ")" ::: "memory"); SB0(); } while (0)
#define VMC(N) asm volatile("s_waitcnt vmcnt(" #N ")" ::: "memory")

// ---- K_t_bias: t = WHT_2048(BB_w[:2048] * z); Sw = 0; bias fastfood ----
__global__ __launch_bounds__(1024) void k_t_bias(const float* __restrict__ z,
                                                 const float* __restrict__ BBw,
                                                 const float* __restrict__ b0,
                                                 const float* __restrict__ BBb,
                                                 const float* __restrict__ GGb,
                                                 const int* __restrict__ Pib,
                                                 float* __restrict__ t_out,
                                                 float* __restrict__ bout,
                                                 float* __restrict__ Sw) {
  __shared__ float u[2048];
  __shared__ float m1[4096];
  __shared__ float m2[4096];
  __shared__ float red[16];
  const int tid = threadIdx.x;
  for (int i = tid; i < 2048; i += 1024) u[i] = BBw[i] * z[i];
  for (int i = tid; i < 4096; i += 1024)
    m1[i] = (i < 2048) ? BBb[i] * z[i] : 0.0f;
  float s = 0.0f;
  for (int i = tid; i < 4096; i += 1024) { float g = GGb[i]; s += g * g; }
  for (int off = 32; off > 0; off >>= 1) s += __shfl_down(s, off);
  if ((tid & 63) == 0) red[tid >> 6] = s;
  __syncthreads();
  for (int len = 1; len < 2048; len <<= 1) {
    if (tid < 1024) {
      int j = tid;
      int a = ((j & ~(len - 1)) << 1) | (j & (len - 1));
      float x = u[a], y = u[a + len];
      u[a] = x + y; u[a + len] = x - y;
    }
    #pragma unroll
    for (int q = 0; q < 2; ++q) {
      int j = q * 1024 + tid;
      int a = ((j & ~(len - 1)) << 1) | (j & (len - 1));
      float x = m1[a], y = m1[a + len];
      m1[a] = x + y; m1[a + len] = x - y;
    }
    __syncthreads();
  }
  {
    int len = 2048;
    #pragma unroll
    for (int q = 0; q < 2; ++q) {
      int j = q * 1024 + tid;
      int a = ((j & ~(len - 1)) << 1) | (j & (len - 1));
      float x = m1[a], y = m1[a + len];
      m1[a] = x + y; m1[a + len] = x - y;
    }
    __syncthreads();
  }
  for (int i = tid; i < 2048; i += 1024) t_out[i] = u[i];
  if (tid == 0) *Sw = 0.0f;
  for (int i = tid; i < 4096; i += 1024) m2[i] = m1[Pib[i]] * GGb[i];
  __syncthreads();
  for (int len = 1; len < 4096; len <<= 1) {
    #pragma unroll
    for (int q = 0; q < 2; ++q) {
      int j = q * 1024 + tid;
      int a = ((j & ~(len - 1)) << 1) | (j & (len - 1));
      float x = m2[a], y = m2[a + len];
      m2[a] = x + y; m2[a + len] = x - y;
    }
    __syncthreads();
  }
  float Sb = 0.0f;
  #pragma unroll
  for (int i = 0; i < 16; ++i) Sb += red[i];
  const float scale = 1.0f / sqrtf(Sb * 4096.0f);
  for (int i = tid; i < 4096; i += 1024) bout[i] = b0[i] + m2[i] * scale;
}

// ---- K1: per-row gather (t LDS table) + WHT_2048 along f; bf16 out ----
__global__ __launch_bounds__(256) void k_gather_pass1(const float* __restrict__ t,
                                                      const int* __restrict__ Piw,
                                                      const float* __restrict__ GGw,
                                                      __hip_bfloat16* __restrict__ mout,
                                                      float* __restrict__ Sw) {
  __shared__ float tl[2048];
  __shared__ float row[2048];
  __shared__ float red[4];
  const int tid = threadIdx.x;
  const size_t p0 = (size_t)blockIdx.x * 2048;
  for (int i = tid; i < 2048; i += 256) tl[i] = t[i];
  __syncthreads();
  float s = 0.0f;
  #pragma unroll
  for (int q = 0; q < 8; ++q) {
    int i = q * 256 + tid;
    int pi = Piw[p0 + i];
    float g = GGw[p0 + i];
    row[i] = tl[pi & 2047] * g;
    s += g * g;
  }
  for (int off = 32; off > 0; off >>= 1) s += __shfl_down(s, off);
  if ((tid & 63) == 0) red[tid >> 6] = s;
  __syncthreads();
  if (tid == 0) atomicAdd(Sw, red[0] + red[1] + red[2] + red[3]);
  for (int len = 1; len < 2048; len <<= 1) {
    #pragma unroll
    for (int q = 0; q < 4; ++q) {
      int j = q * 256 + tid;
      int a = ((j & ~(len - 1)) << 1) | (j & (len - 1));
      float x = row[a], y = row[a + len];
      row[a] = x + y; row[a + len] = x - y;
    }
    __syncthreads();
  }
  for (int i = tid; i < 2048; i += 256)
    mout[p0 + i] = __float2bfloat16(row[i]);
}

// ---- K2a: in-register WHT_64 over o_lo (stride 2048), bf16 in/out ----
__global__ __launch_bounds__(256) void k_pass2a(__hip_bfloat16* __restrict__ m) {
  const int tg = blockIdx.x * 256 + threadIdx.x;
  const int f = tg & 2047;
  const int oh = tg >> 11;
  const size_t base = (size_t)oh * 131072 + (size_t)f;
  float v[64];
  #pragma unroll
  for (int s = 0; s < 64; ++s) v[s] = __bfloat162float(m[base + (size_t)s * 2048]);
  #pragma unroll
  for (int len = 1; len < 64; len <<= 1) {
    #pragma unroll
    for (int j = 0; j < 32; ++j) {
      int a = ((j & ~(len - 1)) << 1) | (j & (len - 1));
      float x = v[a], y = v[a + len];
      v[a] = x + y; v[a + len] = x - y;
    }
  }
  #pragma unroll
  for (int s = 0; s < 64; ++s) m[base + (size_t)s * 2048] = __float2bfloat16(v[s]);
}

// ---- K2b: WHT_64 over o_hi (stride 131072) + epilogue W=bf16(W0+scale*m) ----
__global__ __launch_bounds__(256) void k_pass2b_epi(const __hip_bfloat16* __restrict__ m,
                                                    const float* __restrict__ W0,
                                                    const float* __restrict__ Sw,
                                                    __hip_bfloat16* __restrict__ Wb) {
  const int tg = blockIdx.x * 256 + threadIdx.x;
  const int f = tg & 2047;
  const int ol = tg >> 11;
  const size_t base = (size_t)ol * 2048 + (size_t)f;
  float v[64];
  #pragma unroll
  for (int s = 0; s < 64; ++s) v[s] = __bfloat162float(m[base + (size_t)s * 131072]);
  #pragma unroll
  for (int len = 1; len < 64; len <<= 1) {
    #pragma unroll
    for (int j = 0; j < 32; ++j) {
      int a = ((j & ~(len - 1)) << 1) | (j & (len - 1));
      float x = v[a], y = v[a + len];
      v[a] = x + y; v[a + len] = x - y;
    }
  }
  const float scale = 1.0f / sqrtf((*Sw) * 8388608.0f);
  #pragma unroll
  for (int s = 0; s < 64; ++s) {
    size_t idx = base + (size_t)s * 131072;
    Wb[idx] = __float2bfloat16(W0[idx] + v[s] * scale);
  }
}

// ---- K_xcast: x (f32) -> bf16 ----
__global__ __launch_bounds__(256) void k_xcast(const float* __restrict__ x,
                                               __hip_bfloat16* __restrict__ xb) {
  const int i = (blockIdx.x * 256 + threadIdx.x) * 4;
  float4 xv = *reinterpret_cast<const float4*>(x + i);
  __hip_bfloat16 h0 = __float2bfloat16(xv.x);
  __hip_bfloat16 h1 = __float2bfloat16(xv.y);
  __hip_bfloat16 h2 = __float2bfloat16(xv.z);
  __hip_bfloat16 h3 = __float2bfloat16(xv.w);
  ushort4 pk = make_ushort4(*reinterpret_cast<unsigned short*>(&h0),
                            *reinterpret_cast<unsigned short*>(&h1),
                            *reinterpret_cast<unsigned short*>(&h2),
                            *reinterpret_cast<unsigned short*>(&h3));
  *reinterpret_cast<ushort4*>(xb + i) = pk;
}

// ---- GEMM: C[4096][4096] = A[4096][2048] * B[4096][2048]^T + bias ----
// Faithful m201-style 8-phase template: 256x256 tile, BK=64, 8 waves (2Mx4N),
// 2 K-tiles/iter, reads 12/4/8/0 per K-tile w/ same-phase lgkm(0), 2 stage
// loads every phase, vmcnt(2) gates at phases 4 and 8 only.
__global__ __launch_bounds__(512, 2) void k_gemm(const __hip_bfloat16* __restrict__ A,
                                                 const __hip_bfloat16* __restrict__ B,
                                                 const float* __restrict__ bias,
                                                 float* __restrict__ C) {
  constexpr int K = 2048, N = 4096, NT = K / 64;  // 32 K-tiles, 16 iters
  __shared__ __hip_bfloat16 As[2][256 * 64];
  __shared__ __hip_bfloat16 Bs[2][256 * 64];
  const int tid = threadIdx.x;
  const int wave = tid >> 6, lane = tid & 63;
  const int bid = blockIdx.x;
  const int swz = (bid & 7) * 32 + (bid >> 3);   // 256 % 8 == 0 -> bijective
  const int row0 = (swz & 15) * 256;
  const int col0 = (swz >> 4) * 256;
  const int wr = wave >> 2, wc = wave & 3;       // 2M x 4N wave grid
  const int srow = tid >> 3;                     // row in 64-row chunk
  const int gslot = (tid & 7) ^ (srow & 7);      // pre-swizzled global slot
  const int ldst = tid * 8;                      // linear LDS dest (elements)
  const int lr = lane & 15, lk = lane >> 4;

  f32x4 acc[8][4] = {};
  bf16x8 a0[4][2], a1[4][2], b0[2][2], b1[2][2];

  // stage one 64-row chunk (2 chunks = 1 half-tile = 2 calls)
  #define STAGE_A(BUF, KT, CH0)                                                 \
    { _Pragma("unroll") for (int c = 0; c < 2; ++c)                             \
        load_lds16(A + (size_t)(row0 + (CH0 + c) * 64 + srow) * K + (KT) * 64 + gslot * 8, \
                   &As[BUF][(CH0 + c) * 4096 + ldst]); }
  #define STAGE_B(BUF, KT, CH0)                                                 \
    { _Pragma("unroll") for (int c = 0; c < 2; ++c)                             \
        load_lds16(B + (size_t)(col0 + (CH0 + c) * 64 + srow) * K + (KT) * 64 + gslot * 8, \
                   &Bs[BUF][(CH0 + c) * 4096 + ldst]); }

  #define READ_A(DST, BUF, HALF)                                                \
    { _Pragma("unroll") for (int i = 0; i < 4; ++i)                             \
        _Pragma("unroll") for (int ks = 0; ks < 2; ++ks) {                      \
          int row = wr * 128 + (HALF) * 64 + i * 16 + lr;                       \
          DST[i][ks] = *(const bf16x8*)&As[BUF][row * 64 + (((ks * 4 + lk) ^ (row & 7)) * 8)]; } }
  #define READ_B(DST, BUF, HALF)                                                \
    { _Pragma("unroll") for (int j = 0; j < 2; ++j)                             \
        _Pragma("unroll") for (int ks = 0; ks < 2; ++ks) {                      \
          int row = wc * 64 + (HALF) * 32 + j * 16 + lr;                        \
          DST[j][ks] = *(const bf16x8*)&Bs[BUF][row * 64 + (((ks * 4 + lk) ^ (row & 7)) * 8)]; } }

  #define MFMA16(AF, BF, IO, JO)                                                \
    { __builtin_amdgcn_s_setprio(1);                                            \
      _Pragma("unroll") for (int i = 0; i < 4; ++i)                             \
        _Pragma("unroll") for (int j = 0; j < 2; ++j)                           \
          _Pragma("unroll") for (int ks = 0; ks < 2; ++ks)                      \
            acc[(IO) + i][(JO) + j] =                                           \
              __builtin_amdgcn_mfma_f32_16x16x32_bf16(AF[i][ks], BF[j][ks],     \
                                                      acc[(IO) + i][(JO) + j], 0, 0, 0); \
      __builtin_amdgcn_s_setprio(0); }

  // ---- prologue: tile0 full -> buf0; A(1) half0 -> buf1; gate tile0 ----
  STAGE_A(0, 0, 0) STAGE_A(0, 0, 2) STAGE_B(0, 0, 0) STAGE_B(0, 0, 2)
  STAGE_A(1, 1, 0)
  VMC(2);
  BAR();

  for (int it = 0; it < 16; ++it) {
    const int u = 2 * it;
    const int v = u + 1;
    const int u2 = (u + 2 < NT) ? u + 2 : NT - 1;
    const int u3 = (u + 3 < NT) ? u + 3 : NT - 1;

    // ===== phase 1: tile u q00; reads a0,b0 (12); stage A(v) h1 =====
    READ_A(a0, 0, 0) READ_B(b0, 0, 0)
    STAGE_A(1, v, 2)
    LGKM(8);
    BAR(); LGKM(0);
    MFMA16(a0, b0, 0, 0)
    BAR();
    // ===== phase 2: q01; reads b1 (4); stage B(v) h0 =====
    READ_B(b1, 0, 1)
    STAGE_B(1, v, 0)
    BAR(); LGKM(0);
    MFMA16(a0, b1, 0, 2)
    BAR();
    // ===== phase 3: q11; reads a1 (8); stage B(v) h1 =====
    READ_A(a1, 0, 1)
    STAGE_B(1, v, 2)
    BAR(); LGKM(0);
    MFMA16(a1, b1, 4, 2)
    BAR();
    // ===== phase 4: q10; no reads; stage A(u+2) h0; gate tile v =====
    STAGE_A(0, u2, 0)
    BAR();
    MFMA16(a1, b0, 4, 0)
    VMC(2);
    BAR();

    // ===== phase 5: tile v q00; reads (12); stage A(u+2) h1 =====
    READ_A(a0, 1, 0) READ_B(b0, 1, 0)
    STAGE_A(0, u2, 2)
    LGKM(8);
    BAR(); LGKM(0);
    MFMA16(a0, b0, 0, 0)
    BAR();
    // ===== phase 6: q01; reads b1 (4); stage B(u+2) h0 =====
    READ_B(b1, 1, 1)
    STAGE_B(0, u2, 0)
    BAR(); LGKM(0);
    MFMA16(a0, b1, 0, 2)
    BAR();
    // ===== phase 7: q11; reads a1 (8); stage B(u+2) h1 =====
    READ_A(a1, 1, 1)
    STAGE_B(0, u2, 2)
    BAR(); LGKM(0);
    MFMA16(a1, b1, 4, 2)
    BAR();
    // ===== phase 8: q10; no reads; stage A(u+3) h0; gate tile u+2 =====
    STAGE_A(1, u3, 0)
    BAR();
    MFMA16(a1, b0, 4, 0)
    VMC(2);
    BAR();
  }

  // ---- epilogue: C = acc + bias ----
  #pragma unroll
  for (int j = 0; j < 4; ++j) {
    const int col = col0 + wc * 64 + j * 16 + lr;
    const float bv = bias[col];
    #pragma unroll
    for (int i = 0; i < 8; ++i) {
      const int row = row0 + wr * 128 + i * 16 + lk * 4;
      #pragma unroll
      for (int q = 0; q < 4; ++q)
        C[(size_t)(row + q) * N + col] = acc[i][j][q] + bv;
    }
  }
  #undef STAGE_A
  #undef STAGE_B
  #undef READ_A
  #undef READ_B
  #undef MFMA16
}

extern "C" void kernel_launch(void* const* d_in, const int* in_sizes, int n_in,
                              void* d_out, int out_size, void* d_ws, size_t ws_size,
                              hipStream_t stream) {
  (void)in_sizes; (void)n_in; (void)out_size; (void)ws_size;
  const float* x   = (const float*)d_in[0];
  const float* z   = (const float*)d_in[1];
  const float* W0  = (const float*)d_in[2];
  const float* b0  = (const float*)d_in[3];
  const float* BBw = (const float*)d_in[4];
  const float* GGw = (const float*)d_in[5];
  const float* BBb = (const float*)d_in[6];
  const float* GGb = (const float*)d_in[7];
  const int*   Piw = (const int*)d_in[8];
  const int*   Pib = (const int*)d_in[9];
  float* out = (float*)d_out;

  char* ws = (char*)d_ws;
  float* t_buf = (float*)(ws);                                   // 2048 f
  float* b_buf = (float*)(ws + 8192);                            // 4096 f
  float* Sw    = (float*)(ws + 24576);                           // 1 f
  __hip_bfloat16* m_buf = (__hip_bfloat16*)(ws + 32768);                    // 2^23 bf16 (16MB)
  __hip_bfloat16* Wb = (__hip_bfloat16*)(ws + 32768 + 16777216);            // 16MB
  __hip_bfloat16* xb = (__hip_bfloat16*)(ws + 32768 + 16777216 + 16777216); // 16MB

  k_xcast<<<8192, 256, 0, stream>>>(x, xb);
  k_t_bias<<<1, 1024, 0, stream>>>(z, BBw, b0, BBb, GGb, Pib, t_buf, b_buf, Sw);
  k_gather_pass1<<<4096, 256, 0, stream>>>(t_buf, Piw, GGw, m_buf, Sw);
  k_pass2a<<<512, 256, 0, stream>>>(m_buf);
  k_pass2b_epi<<<512, 256, 0, stream>>>(m_buf, W0, Sw, Wb);
  k_gemm<<<256, 512, 0, stream>>>(xb, Wb, b_buf, out);
}

// Round 5
// 183.144 us; speedup vs baseline: 1.0454x; 1.0454x over previous
//
#include <hip/hip_runtime.h>
#include <hip/hip_bf16.h>
#include <math.h>

typedef __bf16  bf16x8 __attribute__((ext_vector_type(8)));
typedef float   f32x4  __attribute__((ext_vector_type(4)));

// ---------------- helpers ----------------
static __device__ __forceinline__ void load_lds16(const void* g, void* l) {
  __builtin_amdgcn_global_load_lds(
      (const __attribute__((address_space(1))) void*)(g),
      (__attribute__((address_space(3))) void*)(l), 16, 0, 0);
}

#define BAR() __builtin_amdgcn_s_barrier()
#define SB0() __builtin_amdgcn_sched_barrier(0)
#define LGKM(N) do { asm volatile("s_waitcnt lgkmcnt(" #N ")" ::: "memory"); SB0(); } while (0)
#define VMC(N) asm volatile("s_waitcnt vmcnt(" #N ")" ::: "memory")

// ---- K_pre: block 0 = {t = WHT_2048(BBw*z); Sw=0; bias fastfood}; others xcast ----
__global__ __launch_bounds__(1024) void k_pre(const float* __restrict__ x,
                                              __hip_bfloat16* __restrict__ xb,
                                              const float* __restrict__ z,
                                              const float* __restrict__ BBw,
                                              const float* __restrict__ b0,
                                              const float* __restrict__ BBb,
                                              const float* __restrict__ GGb,
                                              const int* __restrict__ Pib,
                                              float* __restrict__ t_out,
                                              float* __restrict__ bout,
                                              float* __restrict__ Sw) {
  const int tid = threadIdx.x;
  if (blockIdx.x != 0) {
    const int i = ((blockIdx.x - 1) * 1024 + tid) * 4;   // exact cover: 2048*1024*4 = 2^23
    float4 xv = *reinterpret_cast<const float4*>(x + i);
    __hip_bfloat16 h0 = __float2bfloat16(xv.x);
    __hip_bfloat16 h1 = __float2bfloat16(xv.y);
    __hip_bfloat16 h2 = __float2bfloat16(xv.z);
    __hip_bfloat16 h3 = __float2bfloat16(xv.w);
    ushort4 pk = make_ushort4(*reinterpret_cast<unsigned short*>(&h0),
                              *reinterpret_cast<unsigned short*>(&h1),
                              *reinterpret_cast<unsigned short*>(&h2),
                              *reinterpret_cast<unsigned short*>(&h3));
    *reinterpret_cast<ushort4*>(xb + i) = pk;
    return;
  }
  __shared__ float u[2048];
  __shared__ float m1[4096];
  __shared__ float m2[4096];
  __shared__ float red[16];
  for (int i = tid; i < 2048; i += 1024) u[i] = BBw[i] * z[i];
  for (int i = tid; i < 4096; i += 1024)
    m1[i] = (i < 2048) ? BBb[i] * z[i] : 0.0f;
  float s = 0.0f;
  for (int i = tid; i < 4096; i += 1024) { float g = GGb[i]; s += g * g; }
  for (int off = 32; off > 0; off >>= 1) s += __shfl_down(s, off);
  if ((tid & 63) == 0) red[tid >> 6] = s;
  __syncthreads();
  for (int len = 1; len < 2048; len <<= 1) {
    if (tid < 1024) {
      int j = tid;
      int a = ((j & ~(len - 1)) << 1) | (j & (len - 1));
      float xx = u[a], y = u[a + len];
      u[a] = xx + y; u[a + len] = xx - y;
    }
    #pragma unroll
    for (int q = 0; q < 2; ++q) {
      int j = q * 1024 + tid;
      int a = ((j & ~(len - 1)) << 1) | (j & (len - 1));
      float xx = m1[a], y = m1[a + len];
      m1[a] = xx + y; m1[a + len] = xx - y;
    }
    __syncthreads();
  }
  {
    int len = 2048;
    #pragma unroll
    for (int q = 0; q < 2; ++q) {
      int j = q * 1024 + tid;
      int a = ((j & ~(len - 1)) << 1) | (j & (len - 1));
      float xx = m1[a], y = m1[a + len];
      m1[a] = xx + y; m1[a + len] = xx - y;
    }
    __syncthreads();
  }
  for (int i = tid; i < 2048; i += 1024) t_out[i] = u[i];
  if (tid == 0) *Sw = 0.0f;
  for (int i = tid; i < 4096; i += 1024) m2[i] = m1[Pib[i]] * GGb[i];
  __syncthreads();
  for (int len = 1; len < 4096; len <<= 1) {
    #pragma unroll
    for (int q = 0; q < 2; ++q) {
      int j = q * 1024 + tid;
      int a = ((j & ~(len - 1)) << 1) | (j & (len - 1));
      float xx = m2[a], y = m2[a + len];
      m2[a] = xx + y; m2[a + len] = xx - y;
    }
    __syncthreads();
  }
  float Sb = 0.0f;
  #pragma unroll
  for (int i = 0; i < 16; ++i) Sb += red[i];
  const float scale = 1.0f / sqrtf(Sb * 4096.0f);
  for (int i = tid; i < 4096; i += 1024) bout[i] = b0[i] + m2[i] * scale;
}

// ---- K1: per-row gather (t LDS table) + WHT_2048 along f; bf16 out ----
__global__ __launch_bounds__(256) void k_gather_pass1(const float* __restrict__ t,
                                                      const int* __restrict__ Piw,
                                                      const float* __restrict__ GGw,
                                                      __hip_bfloat16* __restrict__ mout,
                                                      float* __restrict__ Sw) {
  __shared__ float tl[2048];
  __shared__ float row[2048];
  __shared__ float red[4];
  const int tid = threadIdx.x;
  const size_t p0 = (size_t)blockIdx.x * 2048;
  for (int i = tid; i < 2048; i += 256) tl[i] = t[i];
  __syncthreads();
  float s = 0.0f;
  #pragma unroll
  for (int q = 0; q < 8; ++q) {
    int i = q * 256 + tid;
    int pi = Piw[p0 + i];
    float g = GGw[p0 + i];
    row[i] = tl[pi & 2047] * g;
    s += g * g;
  }
  for (int off = 32; off > 0; off >>= 1) s += __shfl_down(s, off);
  if ((tid & 63) == 0) red[tid >> 6] = s;
  __syncthreads();
  if (tid == 0) atomicAdd(Sw, red[0] + red[1] + red[2] + red[3]);
  for (int len = 1; len < 2048; len <<= 1) {
    #pragma unroll
    for (int q = 0; q < 4; ++q) {
      int j = q * 256 + tid;
      int a = ((j & ~(len - 1)) << 1) | (j & (len - 1));
      float x = row[a], y = row[a + len];
      row[a] = x + y; row[a + len] = x - y;
    }
    __syncthreads();
  }
  for (int i = tid; i < 2048; i += 256)
    mout[p0 + i] = __float2bfloat16(row[i]);
}

// ---- K2a: in-register WHT_64 over o_lo (stride 2048), bf16 in/out ----
__global__ __launch_bounds__(256) void k_pass2a(__hip_bfloat16* __restrict__ m) {
  const int tg = blockIdx.x * 256 + threadIdx.x;
  const int f = tg & 2047;
  const int oh = tg >> 11;
  const size_t base = (size_t)oh * 131072 + (size_t)f;
  float v[64];
  #pragma unroll
  for (int s = 0; s < 64; ++s) v[s] = __bfloat162float(m[base + (size_t)s * 2048]);
  #pragma unroll
  for (int len = 1; len < 64; len <<= 1) {
    #pragma unroll
    for (int j = 0; j < 32; ++j) {
      int a = ((j & ~(len - 1)) << 1) | (j & (len - 1));
      float x = v[a], y = v[a + len];
      v[a] = x + y; v[a + len] = x - y;
    }
  }
  #pragma unroll
  for (int s = 0; s < 64; ++s) m[base + (size_t)s * 2048] = __float2bfloat16(v[s]);
}

// ---- K2b: WHT_64 over o_hi (stride 131072) + epilogue W=bf16(W0+scale*m) ----
__global__ __launch_bounds__(256) void k_pass2b_epi(const __hip_bfloat16* __restrict__ m,
                                                    const float* __restrict__ W0,
                                                    const float* __restrict__ Sw,
                                                    __hip_bfloat16* __restrict__ Wb) {
  const int tg = blockIdx.x * 256 + threadIdx.x;
  const int f = tg & 2047;
  const int ol = tg >> 11;
  const size_t base = (size_t)ol * 2048 + (size_t)f;
  float v[64];
  #pragma unroll
  for (int s = 0; s < 64; ++s) v[s] = __bfloat162float(m[base + (size_t)s * 131072]);
  #pragma unroll
  for (int len = 1; len < 64; len <<= 1) {
    #pragma unroll
    for (int j = 0; j < 32; ++j) {
      int a = ((j & ~(len - 1)) << 1) | (j & (len - 1));
      float x = v[a], y = v[a + len];
      v[a] = x + y; v[a + len] = x - y;
    }
  }
  const float scale = 1.0f / sqrtf((*Sw) * 8388608.0f);
  #pragma unroll
  for (int s = 0; s < 64; ++s) {
    size_t idx = base + (size_t)s * 131072;
    Wb[idx] = __float2bfloat16(W0[idx] + v[s] * scale);
  }
}

// ---- GEMM: C[4096][4096] = A[4096][2048] * B[4096][2048]^T + bias ----
// 256x256, BK=64, 8 waves (2Mx4N), 8-phase, 1 half-tile staged per phase,
// deep counted gates: VMC(4)@ph1,ph4,ph5; VMC(6)@ph8 (min 2-phase slack).
// Epilogue: VMC(0) drain, LDS-staged coalesced dwordx4 C stores.
__global__ __launch_bounds__(512, 2) void k_gemm(const __hip_bfloat16* __restrict__ A,
                                                 const __hip_bfloat16* __restrict__ B,
                                                 const float* __restrict__ bias,
                                                 float* __restrict__ C) {
  constexpr int K = 2048, N = 4096, NT = K / 64;  // 32 K-tiles, 16 iters
  __shared__ __hip_bfloat16 As[2][256 * 64];
  __shared__ __hip_bfloat16 Bs[2][256 * 64];
  const int tid = threadIdx.x;
  const int wave = tid >> 6, lane = tid & 63;
  const int bid = blockIdx.x;
  const int swz = (bid & 7) * 32 + (bid >> 3);   // 256 % 8 == 0 -> bijective
  const int row0 = (swz & 15) * 256;
  const int col0 = (swz >> 4) * 256;
  const int wr = wave >> 2, wc = wave & 3;       // 2M x 4N wave grid
  const int srow = tid >> 3;                     // row in 64-row chunk
  const int gslot = (tid & 7) ^ (srow & 7);      // pre-swizzled global slot
  const int ldst = tid * 8;                      // linear LDS dest (elements)
  const int lr = lane & 15, lk = lane >> 4;

  f32x4 acc[8][4] = {};
  bf16x8 a0[4][2], a1[4][2], b0[2][2], b1[2][2];

  #define STAGE_A(BUF, KT, CH0)                                                 \
    { _Pragma("unroll") for (int c = 0; c < 2; ++c)                             \
        load_lds16(A + (size_t)(row0 + (CH0 + c) * 64 + srow) * K + (KT) * 64 + gslot * 8, \
                   &As[BUF][(CH0 + c) * 4096 + ldst]); }
  #define STAGE_B(BUF, KT, CH0)                                                 \
    { _Pragma("unroll") for (int c = 0; c < 2; ++c)                             \
        load_lds16(B + (size_t)(col0 + (CH0 + c) * 64 + srow) * K + (KT) * 64 + gslot * 8, \
                   &Bs[BUF][(CH0 + c) * 4096 + ldst]); }

  #define READ_A(DST, BUF, HALF)                                                \
    { _Pragma("unroll") for (int i = 0; i < 4; ++i)                             \
        _Pragma("unroll") for (int ks = 0; ks < 2; ++ks) {                      \
          int row = wr * 128 + (HALF) * 64 + i * 16 + lr;                       \
          DST[i][ks] = *(const bf16x8*)&As[BUF][row * 64 + (((ks * 4 + lk) ^ (row & 7)) * 8)]; } }
  #define READ_B(DST, BUF, HALF)                                                \
    { _Pragma("unroll") for (int j = 0; j < 2; ++j)                             \
        _Pragma("unroll") for (int ks = 0; ks < 2; ++ks) {                      \
          int row = wc * 64 + (HALF) * 32 + j * 16 + lr;                        \
          DST[j][ks] = *(const bf16x8*)&Bs[BUF][row * 64 + (((ks * 4 + lk) ^ (row & 7)) * 8)]; } }

  #define MFMA16(AF, BF, IO, JO)                                                \
    { __builtin_amdgcn_s_setprio(1);                                            \
      _Pragma("unroll") for (int i = 0; i < 4; ++i)                             \
        _Pragma("unroll") for (int j = 0; j < 2; ++j)                           \
          _Pragma("unroll") for (int ks = 0; ks < 2; ++ks)                      \
            acc[(IO) + i][(JO) + j] =                                           \
              __builtin_amdgcn_mfma_f32_16x16x32_bf16(AF[i][ks], BF[j][ks],     \
                                                      acc[(IO) + i][(JO) + j], 0, 0, 0); \
      __builtin_amdgcn_s_setprio(0); }

  // ---- prologue: A(0)h0,B(0)h0,A(0)h1,B(0)h1,A(1)h0; drain first 2 halves ----
  STAGE_A(0, 0, 0) STAGE_B(0, 0, 0) STAGE_A(0, 0, 2) STAGE_B(0, 0, 2)
  STAGE_A(1, 1, 0)
  VMC(6);   // A(0)h0,B(0)h0 landed; queue = [A(0)h1, B(0)h1, A(1)h0]
  BAR();

  for (int it = 0; it < 16; ++it) {
    const int u = 2 * it;
    const int v = u + 1;
    const int u2 = (u + 2 < NT) ? u + 2 : NT - 1;
    const int u3 = (u + 3 < NT) ? u + 3 : NT - 1;

    // ===== ph1: reads a0,b0 (buf0); stage A(v)h1; gate VMC(4) =====
    READ_A(a0, 0, 0) READ_B(b0, 0, 0)
    STAGE_A(1, v, 2)
    LGKM(8);
    BAR(); LGKM(0);
    MFMA16(a0, b0, 0, 0)
    VMC(4);   // A(u)h1, B(u)h1 landed (for ph2/ph3 reads)
    BAR();
    // ===== ph2: reads b1 (buf0); stage B(v)h0 =====
    READ_B(b1, 0, 1)
    STAGE_B(1, v, 0)
    BAR(); LGKM(0);
    MFMA16(a0, b1, 0, 2)
    BAR();
    // ===== ph3: reads a1 (buf0); stage B(v)h1 =====
    READ_A(a1, 0, 1)
    STAGE_B(1, v, 2)
    BAR(); LGKM(0);
    MFMA16(a1, b1, 4, 2)
    BAR();
    // ===== ph4: stage A(u+2)h0 -> buf0; gate VMC(4) =====
    STAGE_A(0, u2, 0)
    BAR();
    MFMA16(a1, b0, 4, 0)
    VMC(4);   // through B(v)h0 landed (A(v)h0/h1 older, also landed)
    BAR();

    // ===== ph5: reads a0,b0 (buf1); stage B(u+2)h0 -> buf0; gate VMC(4) =====
    READ_A(a0, 1, 0) READ_B(b0, 1, 0)
    STAGE_B(0, u2, 0)
    LGKM(8);
    BAR(); LGKM(0);
    MFMA16(a0, b0, 0, 0)
    VMC(4);   // B(v)h1 landed (for ph6 read)
    BAR();
    // ===== ph6: reads b1 (buf1); stage A(u+2)h1 -> buf0 =====
    READ_B(b1, 1, 1)
    STAGE_A(0, u2, 2)
    BAR(); LGKM(0);
    MFMA16(a0, b1, 0, 2)
    BAR();
    // ===== ph7: reads a1 (buf1); stage B(u+2)h1 -> buf0 =====
    READ_A(a1, 1, 1)
    STAGE_B(0, u2, 2)
    BAR(); LGKM(0);
    MFMA16(a1, b1, 4, 2)
    BAR();
    // ===== ph8: stage A(u+3)h0 -> buf1; gate VMC(6) =====
    STAGE_A(1, u3, 0)
    BAR();
    MFMA16(a1, b0, 4, 0)
    VMC(6);   // A(u+2)h0, B(u+2)h0 landed; queue = [A(u+2)h1, B(u+2)h1, A(u+3)h0]
    BAR();
  }

  // ---- epilogue: drain staging, then LDS-staged coalesced C stores ----
  VMC(0);     // in-flight global_load_lds must land before LDS reuse
  float bv[4];
  #pragma unroll
  for (int j = 0; j < 4; ++j) bv[j] = bias[col0 + wc * 64 + j * 16 + lr];
  float* eps = (float*)&As[0][0];   // 64 KB = 64 rows x 256 cols f32
  #pragma unroll
  for (int r = 0; r < 4; ++r) {
    BAR();
    if (wr == (r >> 1)) {
      const int i0 = (r & 1) * 4;
      #pragma unroll
      for (int i = 0; i < 4; ++i)
        #pragma unroll
        for (int j = 0; j < 4; ++j)
          #pragma unroll
          for (int q = 0; q < 4; ++q) {
            int lrow = i * 16 + lk * 4 + q;          // 0..63
            int col = wc * 64 + j * 16 + lr;
            eps[lrow * 256 + col] = acc[i0 + i][j][q] + bv[j];
          }
    }
    BAR();
    #pragma unroll
    for (int s = 0; s < 8; ++s) {
      int idx = s * 512 + tid;                       // 0..4095
      int lrow = idx >> 6;
      int g = idx & 63;
      f32x4 vv = *(const f32x4*)&eps[lrow * 256 + g * 4];
      *(f32x4*)&C[(size_t)(row0 + r * 64 + lrow) * N + col0 + g * 4] = vv;
    }
  }
  #undef STAGE_A
  #undef STAGE_B
  #undef READ_A
  #undef READ_B
  #undef MFMA16
}

extern "C" void kernel_launch(void* const* d_in, const int* in_sizes, int n_in,
                              void* d_out, int out_size, void* d_ws, size_t ws_size,
                              hipStream_t stream) {
  (void)in_sizes; (void)n_in; (void)out_size; (void)ws_size;
  const float* x   = (const float*)d_in[0];
  const float* z   = (const float*)d_in[1];
  const float* W0  = (const float*)d_in[2];
  const float* b0  = (const float*)d_in[3];
  const float* BBw = (const float*)d_in[4];
  const float* GGw = (const float*)d_in[5];
  const float* BBb = (const float*)d_in[6];
  const float* GGb = (const float*)d_in[7];
  const int*   Piw = (const int*)d_in[8];
  const int*   Pib = (const int*)d_in[9];
  float* out = (float*)d_out;

  char* ws = (char*)d_ws;
  float* t_buf = (float*)(ws);                                   // 2048 f
  float* b_buf = (float*)(ws + 8192);                            // 4096 f
  float* Sw    = (float*)(ws + 24576);                           // 1 f
  __hip_bfloat16* m_buf = (__hip_bfloat16*)(ws + 32768);                    // 2^23 bf16 (16MB)
  __hip_bfloat16* Wb = (__hip_bfloat16*)(ws + 32768 + 16777216);            // 16MB
  __hip_bfloat16* xb = (__hip_bfloat16*)(ws + 32768 + 16777216 + 16777216); // 16MB

  k_pre<<<2049, 1024, 0, stream>>>(x, xb, z, BBw, b0, BBb, GGb, Pib, t_buf, b_buf, Sw);
  k_gather_pass1<<<4096, 256, 0, stream>>>(t_buf, Piw, GGw, m_buf, Sw);
  k_pass2a<<<512, 256, 0, stream>>>(m_buf);
  k_pass2b_epi<<<512, 256, 0, stream>>>(m_buf, W0, Sw, Wb);
  k_gemm<<<256, 512, 0, stream>>>(xb, Wb, b_buf, out);
}